// Round 9
// baseline (30288.486 us; speedup 1.0000x reference)
//
#include <hip/hip_runtime.h>
#include <math.h>

static constexpr int T_STEPS = 10000;
static constexpr int I_DIM = 2048;
static constexpr int O_DIM = 512;
static constexpr int NWG = 4;             // cooperating stripe workgroups
static constexpr int NLAUNCH = 32;        // launched blocks; 4 co-XCD winners work
static constexpr int STRIPE = 128;        // outputs per WG
static constexpr int WGS = 512;           // threads per WG (8 waves)
static constexpr int KPAD = 192;          // padded spike list (mean 102.4, sd 9.9)
static constexpr int NSPL = 7;            // gather split across waves 1..7 (wave0 = softmax engine)
static constexpr int GN = 19;             // fixed async gather loads/thread (covers cnt<=133)
static constexpr float PSPD = 0.9512294245007140091f;  // exp(-0.001/0.02)
static constexpr float OUTD = 0.9048374180359595732f;  // exp(-0.001/0.01)
static constexpr float MU = 0.1f;

typedef float __attribute__((ext_vector_type(4))) f32x4;
typedef float __attribute__((ext_vector_type(2))) f32x2;

// stripe-block Wt layout: WtS[w] is (I_DIM+1) x STRIPE, row I_DIM is the zero pad row
static constexpr size_t WT_BLK = (size_t)(I_DIM + 1) * STRIPE;

// ---------------- K1: compress spikes into ordered, PADDED index lists ----------------
__global__ void build_idx_kernel(const float* __restrict__ spikes,
                                 unsigned short* __restrict__ idxl,
                                 int* __restrict__ cnts) {
    int t = blockIdx.x;
    int tid = threadIdx.x;                 // 256 threads
    if (t >= T_STEPS) {                    // pad rows t = T .. T+3
        for (int p = tid; p < KPAD; p += 256) idxl[(size_t)t * KPAD + p] = (unsigned short)I_DIM;
        if (tid == 0) cnts[t] = 0;
        return;
    }
    const float4* row = reinterpret_cast<const float4*>(spikes + (size_t)t * I_DIM);
    float4 a = row[tid * 2];
    float4 b = row[tid * 2 + 1];
    float v[8] = {a.x, a.y, a.z, a.w, b.x, b.y, b.z, b.w};
    unsigned short tmp[8];
    int c = 0;
#pragma unroll
    for (int j = 0; j < 8; ++j)
        if (v[j] != 0.0f) tmp[c++] = (unsigned short)(tid * 8 + j);

    int lane = tid & 63, wid = tid >> 6;
    int x = c;
    for (int d = 1; d < 64; d <<= 1) {
        int y = __shfl_up(x, d);
        if (lane >= d) x += y;
    }
    __shared__ int wtot[4];
    if (lane == 63) wtot[wid] = x;
    __syncthreads();
    int off = x - c;
    for (int w = 0; w < wid; ++w) off += wtot[w];
    int tot = wtot[0] + wtot[1] + wtot[2] + wtot[3];
    if (tot > KPAD) tot = KPAD;
    for (int j = 0; j < c; ++j) {
        int p = off + j;
        if (p < KPAD) idxl[(size_t)t * KPAD + p] = tmp[j];
    }
    for (int p = tid; p < KPAD; p += 256)
        if (p >= tot) idxl[(size_t)t * KPAD + p] = (unsigned short)I_DIM;
    if (tid == 0) cnts[t] = tot;
}

// ---------------- K2a: copy W into mutable row-major workspace ----------------
__global__ void copy_w_kernel(const float* __restrict__ W, float* __restrict__ Wrow) {
    int i = blockIdx.x * blockDim.x + threadIdx.x;
    reinterpret_cast<float4*>(Wrow)[i] = reinterpret_cast<const float4*>(W)[i];
}

// ---------------- K2b: tiled transpose W[O][I] -> stripe blocks WtS[w][i][128] ----------------
__global__ void transpose_kernel(const float* __restrict__ W, float* __restrict__ Wt) {
    __shared__ float tile[32][33];
    int i0 = blockIdx.x * 32;
    int o0 = blockIdx.y * 32;
    int x = threadIdx.x;
    for (int y = threadIdx.y; y < 32; y += 8)
        tile[y][x] = W[(size_t)(o0 + y) * I_DIM + i0 + x];
    __syncthreads();
    for (int y = threadIdx.y; y < 32; y += 8) {
        int o = o0 + x, i = i0 + y;
        Wt[(size_t)(o >> 7) * WT_BLK + (size_t)i * STRIPE + (o & 127)] = tile[x][y];
    }
}

// ---------------- K2c: zero the pad row of each stripe block ----------------
__global__ void zero_pad_row_kernel(float* __restrict__ Wt) {
    int w = threadIdx.x >> 7, c = threadIdx.x & 127;
    Wt[(size_t)w * WT_BLK + (size_t)I_DIM * STRIPE + c] = 0.0f;
}

// light barrier: LDS-drain only; global loads stay in flight
__device__ __forceinline__ void bar() {
    asm volatile("s_waitcnt lgkmcnt(0)" ::: "memory");
    __builtin_amdgcn_sched_barrier(0);
    __builtin_amdgcn_s_barrier();
    __builtin_amdgcn_sched_barrier(0);
}

// wave64 max, uniform result (max associative -> tree bitwise-safe)
__device__ __forceinline__ float wave_max_dpp(float x) {
    int xb = __float_as_int(x);
#define DPPSTEPM(ctrl, rm)                                                          \
    {                                                                               \
        int tt = __builtin_amdgcn_update_dpp(0xff800000, xb, ctrl, rm, 0xf, false); \
        xb = __float_as_int(fmaxf(__int_as_float(xb), __int_as_float(tt)));         \
    }
    DPPSTEPM(0x111, 0xf)
    DPPSTEPM(0x112, 0xf)
    DPPSTEPM(0x114, 0xf)
    DPPSTEPM(0x118, 0xf)
    DPPSTEPM(0x142, 0xa)
    DPPSTEPM(0x143, 0xc)
#undef DPPSTEPM
    return __int_as_float(__builtin_amdgcn_readlane(xb, 63));
}

// wave64 inclusive prefix sum (per-lane); lane63 = wave total
__device__ __forceinline__ float dpp_scan_add(float x) {
#define DPPSTEPA(ctrl, rm)                                                          \
    {                                                                               \
        float tt = __int_as_float(                                                  \
            __builtin_amdgcn_update_dpp(0, __float_as_int(x), ctrl, rm, 0xf, false)); \
        x += tt;                                                                    \
    }
    DPPSTEPA(0x111, 0xf)
    DPPSTEPA(0x112, 0xf)
    DPPSTEPA(0x114, 0xf)
    DPPSTEPA(0x118, 0xf)
    DPPSTEPA(0x142, 0xa)
    DPPSTEPA(0x143, 0xc)
#undef DPPSTEPA
    return x;
}

// ---------------- K3: 4 (ideally co-XCD) stripe workgroups, 10000 steps ----------------
__launch_bounds__(WGS, 1)
__global__ void seq_kernel(const unsigned short* __restrict__ idxl,
                           const int* __restrict__ cnts,
                           const float* __restrict__ u_rand,
                           const float* __restrict__ b_in,
                           float* __restrict__ Wrow,
                           float* __restrict__ Wt,
                           unsigned long long* __restrict__ slow,   // [2][NWG][2] MALL (proven)
                           unsigned long long* __restrict__ fastp,  // [2][NWG][8] L2 lines (64B)
                           int* __restrict__ ctrl,                  // [0..7]=XCD cnt, [8]=leader
                           float* __restrict__ out) {
    __shared__ __align__(16) float psp[I_DIM + 4];
    __shared__ __align__(16) float mk0[I_DIM + 4];   // spike masks, parity double buffer
    __shared__ __align__(16) float mk1[I_DIM + 4];
    __shared__ f32x2 sg[2][NSPL][64];                // double-buffered split-K gather partials
    __shared__ float redE[8], redF[8], redG[2][8];
    __shared__ unsigned short sidx[3][KPAD];         // 3-deep index-list rotation
    __shared__ int s_rr, s_own, s_role;

    const int tid = threadIdx.x;                     // 512 threads = 8 waves
    const int lane = tid & 63;
    const int jw = tid >> 6;                         // wave 0..7

    // ---------- co-XCD claim (liveness independent of XCC_ID truth) ----------
    if (tid == 0) {
        unsigned xcc;
        asm volatile("s_getreg_b32 %0, hwreg(HW_REG_XCC_ID)" : "=s"(xcc));
        xcc &= 7;
        int pos = __hip_atomic_fetch_add(&ctrl[xcc], 1, __ATOMIC_RELAXED,
                                         __HIP_MEMORY_SCOPE_AGENT);
        int role = -1;
        if (pos < NWG) {
            if (pos == NWG - 1) {
                int expected = 0;
                __hip_atomic_compare_exchange_strong(&ctrl[8], &expected, (int)xcc + 1,
                                                     __ATOMIC_RELAXED, __ATOMIC_RELAXED,
                                                     __HIP_MEMORY_SCOPE_AGENT);
            }
            int L = 0, itc = 0;   // some counter reaches NWG by pigeonhole -> CAS fires
            do {
                L = __hip_atomic_load(&ctrl[8], __ATOMIC_RELAXED, __HIP_MEMORY_SCOPE_AGENT);
            } while (L == 0 && ++itc < (1 << 24));
            if (L == (int)xcc + 1) role = pos;
        }
        s_role = role;
    }
    __syncthreads();
    const int w = s_role;
    if (w < 0) return;                               // non-worker blocks exit

    const int i4 = tid * 4;
    const int o0 = w * STRIPE;
    float* __restrict__ WtS = Wt + (size_t)w * WT_BLK;
    const unsigned long long wt_base = (unsigned long long)WtS;

    // ---------------- prologue ----------------
    for (int p = tid; p < I_DIM + 4; p += WGS) { psp[p] = 0.0f; mk0[p] = 0.0f; mk1[p] = 0.0f; }
    for (int p = tid; p < 3 * KPAD; p += WGS) ((unsigned short*)sidx)[p] = idxl[p]; // lists 0,1,2
    if (tid == 0) { s_rr = 0; s_own = 0; }
    __syncthreads();
    const int cnt0 = cnts[0];
    if (tid < KPAD) {
        psp[sidx[0][tid]] = 1.0f;                    // psp(0) = s_0 (pads -> dead slot)
        mk1[sidx[1][tid]] = 1.0f;                    // mask of s_1
    }
    __syncthreads();
    if (jw > 0) {                                    // synchronous stripe gather of G(0), 7-way
        float a0 = 0.0f, a1 = 0.0f;
        for (int k = jw - 1; k < cnt0; k += NSPL) {
            int col = sidx[0][k];
            f32x2 v = *(const f32x2*)(WtS + (size_t)col * STRIPE + lane * 2);
            a0 += v.x; a1 += v.y;
        }
        sg[0][jw - 1][lane] = (f32x2){a0, a1};
    }
    // wave0 persistent stripe state (2 outputs per lane)
    float aA0 = 0.0f, aA1 = 0.0f, b0 = 0.0f, b1 = 0.0f, tr0 = 0.0f, tr1 = 0.0f;
    if (jw == 0) { b0 = b_in[o0 + 2 * lane]; b1 = b_in[o0 + 2 * lane + 1]; }
    int own1 = 0, own2 = 0, col1 = 0, col2 = 0;
    float nw0 = 0.0f, nw1 = 0.0f, nw2 = 0.0f, nw3 = 0.0f;   // persisted winning-row slice
    int cnt_use = cnts[1];
    float u_cur = u_rand[0];
    __syncthreads();

    for (int t = 0; t < T_STEPS; ++t) {
        const int par = t & 1;
        const int cb = par;                          // sg buffer to combine (G(t))
        const int nb = par ^ 1;                      // sg buffer to fill (G(t+1))
        float* mcur = par ? mk1 : mk0;               // cleared now; E scatters s_{t+2}
        float* mnxt = par ? mk0 : mk1;               // holds s_{t+1}

        // ================= P1 =================
        float u_nxt; int cnt_fut;
        {
            const float* up = u_rand + (t + 1 < T_STEPS ? t + 1 : T_STEPS - 1);
            asm volatile("global_load_dword %0, %1, off" : "=&v"(u_nxt) : "v"(up) : "memory");
            const int* cp = cnts + (t + 2);
            asm volatile("global_load_dword %0, %1, off" : "=&v"(cnt_fut) : "v"(cp) : "memory");
        }
        unsigned int pfw = 0;
        if (tid >= 256 && tid < 256 + KPAD / 2) {
            const unsigned int* pp = reinterpret_cast<const unsigned int*>(idxl) +
                                     (size_t)(t + 3) * (KPAD / 2) + (tid - 256);
            asm volatile("global_load_dword %0, %1, off" : "=&v"(pfw) : "v"(pp) : "memory");
        }
        f32x4 mreg = (f32x4){0.0f, 0.0f, 0.0f, 0.0f};
        f32x4 pr = (f32x4){0.0f, 0.0f, 0.0f, 0.0f};

        if (jw > 0) {
            // -------- gather waves: issue G(t+1), chores, own-drain, consume --------
            f32x2 vals[GN];
            {
                const unsigned short* lst = sidx[(t + 1) % 3];
                const int kw = jw - 1;
#pragma unroll
                for (int j = 0; j < GN; ++j) {
                    int col = lst[kw + NSPL * j];
                    unsigned int voff = ((unsigned)col << 9) | ((unsigned)lane << 3);
                    asm volatile("global_load_dwordx2 %0, %1, %2"
                                 : "=&v"(vals[j]) : "v"(voff), "s"(wt_base) : "memory");
                }
            }
            mreg = *(const f32x4*)(mnxt + i4);        // s_{t+1} slice
            if (own1) {                               // 2-deep correction for rr(t-1)
                float gp2 = nw0 * mreg.x + nw1 * mreg.y + nw2 * mreg.z + nw3 * mreg.w;
                float gs = dpp_scan_add(gp2);
                if (lane == 63) redG[par][jw] = gs;
            }
            *(f32x4*)(mcur + i4) = (f32x4){0.0f, 0.0f, 0.0f, 0.0f};
            pr = *(const f32x4*)(psp + i4);
            {
#pragma clang fp contract(off)
                float q0 = pr.x * PSPD; q0 += mreg.x;
                float q1 = pr.y * PSPD; q1 += mreg.y;
                float q2 = pr.z * PSPD; q2 += mreg.z;
                float q3 = pr.w * PSPD; q3 += mreg.w;
                *(f32x4*)(psp + i4) = (f32x4){q0, q1, q2, q3};
            }
            // drain own loads (gathers + u/cnt + pfw) and consume
            asm volatile("s_waitcnt vmcnt(0)" ::: "memory");
            __builtin_amdgcn_sched_barrier(0);
            asm volatile("" : "+v"(cnt_fut), "+v"(u_nxt));
            {
                float a0 = vals[0].x, a1 = vals[0].y;
#pragma unroll
                for (int j = 1; j < GN; ++j) { a0 += vals[j].x; a1 += vals[j].y; }
                if (cnt_use > NSPL * GN) {            // rare tail (cnt > 133)
                    const unsigned short* lst = sidx[(t + 1) % 3];
                    for (int k = NSPL * GN + (jw - 1); k < cnt_use; k += NSPL) {
                        int col = lst[k];
                        f32x2 v = *(const f32x2*)(WtS + (size_t)col * STRIPE + lane * 2);
                        a0 += v.x; a1 += v.y;
                    }
                }
                sg[nb][jw - 1][lane] = (f32x2){a0, a1};
            }
            if (tid >= 256 && tid < 256 + KPAD / 2)   // stage list(t+3)
                ((unsigned int*)sidx[(t + 3) % 3])[tid - 256] = pfw;
        } else {
            // -------- wave0: softmax engine --------
            tr0 *= OUTD; tr1 *= OUTD;
            float v0 = 0.0f, v1 = 0.0f;
#pragma unroll
            for (int j = 0; j < NSPL; ++j) { f32x2 s = sg[cb][j][lane]; v0 += s.x; v1 += s.y; }
            if (own1) {                               // stale fixes for rr(t-1)
                float es = 0.0f, fs = 0.0f;
#pragma unroll
                for (int j = 0; j < 8; ++j) { es += redE[j]; fs += redF[j]; }
                if (lane == (col1 >> 1)) {
                    if (col1 & 1) { aA1 += es; v1 = fs; } else { aA0 += es; v0 = fs; }
                }
            }
            if (own2 && !(own1 && col2 == col1)) {    // 2-deep fix for rr(t-2)
                float gs = 0.0f;
#pragma unroll
                for (int j = 0; j < 8; ++j) gs += redG[par ^ 1][j];
                if (lane == (col2 >> 1)) { if (col2 & 1) v1 = gs; else v0 = gs; }
            }
            aA0 = PSPD * aA0 + v0; aA1 = PSPD * aA1 + v1;
            float z0 = aA0 + b0, z1 = aA1 + b1;
            float m_w = wave_max_dpp(fmaxf(z0, z1));
            float e0 = expf(z0 - m_w), e1 = expf(z1 - m_w);
            float pin = dpp_scan_add(e0 + e1);
            float pex = __int_as_float(
                __builtin_amdgcn_update_dpp(0, __float_as_int(pin), 0x111, 0xf, 0xf, false));
            float p15 = __int_as_float(__builtin_amdgcn_readlane(__float_as_int(pin), 15));
            float p31 = __int_as_float(__builtin_amdgcn_readlane(__float_as_int(pin), 31));
            float p47 = __int_as_float(__builtin_amdgcn_readlane(__float_as_int(pin), 47));
            if (lane == 16) pex = p15;
            if (lane == 32) pex = p31;
            if (lane == 48) pex = p47;
            float S_w = __int_as_float(__builtin_amdgcn_readlane(__float_as_int(pin), 63));
            // dual publish: raw L2 atomics (fast, same-XCD) + AGENT atomics (proven MALL)
            unsigned long long tag = ((unsigned long long)(unsigned)(t + 1)) << 32;
            unsigned long long pm = tag | (unsigned)__float_as_int(m_w);
            unsigned long long ps = tag | (unsigned)__float_as_int(S_w);
            if (lane == 0) {
                unsigned long long* fl = fastp + ((size_t)par * NWG + w) * 8;
                asm volatile("global_atomic_swap_x2 %0, %1, off" :: "v"(fl), "v"(pm) : "memory");
                asm volatile("global_atomic_swap_x2 %0, %1, off" :: "v"(fl + 1), "v"(ps) : "memory");
                unsigned long long* my = slow + (((size_t)par * NWG + w) * 2);
                __hip_atomic_store(my + 0, pm, __ATOMIC_RELAXED, __HIP_MEMORY_SCOPE_AGENT);
                __hip_atomic_store(my + 1, ps, __ATOMIC_RELAXED, __HIP_MEMORY_SCOPE_AGENT);
            }
            // hybrid spin: lanes 0..5 poll fast L2 slots; every 8th iter the MALL slot
            int oi = lane >> 1; oi += (oi >= w) ? 1 : 0; oi &= 3;
            unsigned long long* sp = slow + (((size_t)par * NWG + oi) * 2 + (lane & 1));
            unsigned long long* fp = fastp + ((size_t)par * NWG + oi) * 8 + (lane & 1);
            bool need = (lane < 6);
            unsigned long long got = 0;
            bool ok = !need;
            int it = 0;
            while (!__all(ok)) {
                if (!ok) {
                    unsigned long long g;
                    if ((it & 7) == 7) {
                        g = __hip_atomic_load(sp, __ATOMIC_RELAXED, __HIP_MEMORY_SCOPE_AGENT);
                    } else {
                        unsigned long long z64 = 0;
                        asm volatile("global_atomic_or_x2 %0, %1, %2, off sc0"
                                     : "=&v"(g) : "v"(fp), "v"(z64) : "memory");
                        asm volatile("s_waitcnt vmcnt(0)" ::: "memory");
                        __builtin_amdgcn_sched_barrier(0);
                    }
                    if ((g >> 32) == (unsigned long long)(unsigned)(t + 1)) { got = g; ok = true; }
                }
                if (++it > (1 << 22)) break;          // bounded: no hang
            }
            float pay = __int_as_float((int)(unsigned)got);
            float mj[4], sj[4];
#pragma unroll
            for (int j = 0; j < 4; ++j) {
                if (j == w) { mj[j] = m_w; sj[j] = S_w; }
                else {
                    int pos = j - (j > w ? 1 : 0);
                    mj[j] = __shfl(pay, 2 * pos);
                    sj[j] = __shfl(pay, 2 * pos + 1);
                }
            }
            float M = fmaxf(fmaxf(mj[0], mj[1]), fmaxf(mj[2], mj[3]));
            float o_run = 0.0f, offw = 0.0f, offn = 0.0f, sc_w = 0.0f;
#pragma unroll
            for (int j = 0; j < 4; ++j) {             // identical chain in all WGs
                float sc = expf(mj[j] - M);
                if (j == w) { offw = o_run; sc_w = sc; }
                o_run = fmaf(sj[j], sc, o_run);
                if (j == w) offn = o_run;
            }
            float uQ = u_cur * o_run;
            int owner = (((offw < uQ) || w == 0) && ((uQ <= offn) || w == NWG - 1)) ? 1 : 0;
            if (lane == 0) { s_own = owner; s_rr = STRIPE - 1; }
            if (owner) {
                float cqp0 = fmaf(pex, sc_w, offw);
                float cq0  = fmaf(pex + e0, sc_w, offw);
                float cq1  = fmaf(pin, sc_w, offw);
                bool firstG = (w == 0 && lane == 0);
                bool lastG  = (w == NWG - 1 && lane == 63);
                bool w0c = (cqp0 < uQ || firstG) && (uQ <= cq0);
                bool w1c = (cq0 < uQ) && (uQ <= cq1 || lastG);
                if (w0c) s_rr = 2 * lane;
                if (w1c) s_rr = 2 * lane + 1;
            }
            // drain u/cnt and do deferred chores
            asm volatile("s_waitcnt vmcnt(0)" ::: "memory");
            __builtin_amdgcn_sched_barrier(0);
            asm volatile("" : "+v"(cnt_fut), "+v"(u_nxt));
            mreg = *(const f32x4*)(mnxt + i4);
            if (own1) {
                float gp2 = nw0 * mreg.x + nw1 * mreg.y + nw2 * mreg.z + nw3 * mreg.w;
                float gs = dpp_scan_add(gp2);
                if (lane == 63) redG[par][0] = gs;
            }
            *(f32x4*)(mcur + i4) = (f32x4){0.0f, 0.0f, 0.0f, 0.0f};
            pr = *(const f32x4*)(psp + i4);
            {
#pragma clang fp contract(off)
                float q0 = pr.x * PSPD; q0 += mreg.x;
                float q1 = pr.y * PSPD; q1 += mreg.y;
                float q2 = pr.z * PSPD; q2 += mreg.z;
                float q3 = pr.w * PSPD; q3 += mreg.w;
                *(f32x4*)(psp + i4) = (f32x4){q0, q1, q2, q3};
            }
        }
        bar();  // B1

        // ================= E =================
        const int rr = s_rr;
        const int own = s_own;
        const int rrglob = o0 + rr;
        f32x4 w2 = (f32x4){0.0f, 0.0f, 0.0f, 0.0f};
        if (own) {
            const float* rp = Wrow + (size_t)rrglob * I_DIM + i4;
            asm volatile("global_load_dwordx4 %0, %1, off" : "=&v"(w2) : "v"(rp) : "memory");
        }
        // scatter mask s_{t+2} from list(t+2) (overlaps w2 latency)
        if (tid < KPAD) mcur[sidx[(t + 2) % 3][tid]] = 1.0f;
        if (own) {
            asm volatile("s_waitcnt vmcnt(0)" ::: "memory");   // w2 only outstanding
            __builtin_amdgcn_sched_barrier(0);
            nw0 = w2.x + MU * (expf(-w2.x) * pr.x - 1.0f);
            nw1 = w2.y + MU * (expf(-w2.y) * pr.y - 1.0f);
            nw2 = w2.z + MU * (expf(-w2.z) * pr.z - 1.0f);
            nw3 = w2.w + MU * (expf(-w2.w) * pr.w - 1.0f);
            *(f32x4*)(Wrow + (size_t)rrglob * I_DIM + i4) = (f32x4){nw0, nw1, nw2, nw3};
            WtS[(size_t)(i4 + 0) * STRIPE + rr] = nw0;
            WtS[(size_t)(i4 + 1) * STRIPE + rr] = nw1;
            WtS[(size_t)(i4 + 2) * STRIPE + rr] = nw2;
            WtS[(size_t)(i4 + 3) * STRIPE + rr] = nw3;
            float dp = (nw0 - w2.x) * pr.x + (nw1 - w2.y) * pr.y +
                       (nw2 - w2.z) * pr.z + (nw3 - w2.w) * pr.w;
            float gp = nw0 * mreg.x + nw1 * mreg.y + nw2 * mreg.z + nw3 * mreg.w;
            float ds = dpp_scan_add(dp);
            float gs = dpp_scan_add(gp);
            if (lane == 63) { redE[jw] = ds; redF[jw] = gs; }
            if (jw == 0 && lane == (rr >> 1)) {
                if (rr & 1) { tr1 += 1.0f; b1 = b1 + MU * (expf(-b1) - 1.0f); }
                else        { tr0 += 1.0f; b0 = b0 + MU * (expf(-b0) - 1.0f); }
                out[(size_t)t * O_DIM + rrglob] = 1.0f;
            }
        }
        own2 = own1; col2 = col1;
        own1 = own;  col1 = rr;
        cnt_use = cnt_fut;
        u_cur = u_nxt;
        bar();  // B2
    }

    if (jw == 0) {
        out[(size_t)T_STEPS * O_DIM + o0 + 2 * lane] = tr0;
        out[(size_t)T_STEPS * O_DIM + o0 + 2 * lane + 1] = tr1;
    }
}

extern "C" void kernel_launch(void* const* d_in, const int* in_sizes, int n_in,
                              void* d_out, int out_size, void* d_ws, size_t ws_size,
                              hipStream_t stream) {
    const float* spikes = (const float*)d_in[0];   // [T, I]
    const float* u_rand = (const float*)d_in[1];   // [T]
    const float* W      = (const float*)d_in[2];   // [O, I]
    const float* b      = (const float*)d_in[3];   // [O]
    float* out = (float*)d_out;                    // [T*O + O]

    float* Wrow = (float*)d_ws;                                        // 4 MB
    float* Wt   = Wrow + (size_t)O_DIM * I_DIM;                        // 4 stripe blocks
    unsigned short* idxl = (unsigned short*)(Wt + (size_t)NWG * WT_BLK);
    int* cnts = (int*)(idxl + (size_t)(T_STEPS + 4) * KPAD);
    unsigned long long* slow = (unsigned long long*)(cnts + (T_STEPS + 4));  // 16 u64
    unsigned long long* fastp = (unsigned long long*)
        ((((size_t)(slow + 16)) + 63) & ~(size_t)63);                  // 2*NWG lines x 64B
    int* ctrl = (int*)(fastp + 2 * NWG * 8);                           // 16 ints

    hipMemsetAsync(d_out, 0, (size_t)out_size * sizeof(float), stream);
    hipMemsetAsync(slow, 0, (size_t)((char*)(ctrl + 16) - (char*)slow), stream);

    hipLaunchKernelGGL(build_idx_kernel, dim3(T_STEPS + 4), dim3(256), 0, stream,
                       spikes, idxl, cnts);
    hipLaunchKernelGGL(copy_w_kernel, dim3((O_DIM * I_DIM / 4) / 256), dim3(256), 0, stream,
                       W, Wrow);
    hipLaunchKernelGGL(transpose_kernel, dim3(I_DIM / 32, O_DIM / 32), dim3(32, 8), 0, stream,
                       W, Wt);
    hipLaunchKernelGGL(zero_pad_row_kernel, dim3(1), dim3(NWG * STRIPE), 0, stream, Wt);
    hipLaunchKernelGGL(seq_kernel, dim3(NLAUNCH), dim3(WGS), 0, stream,
                       idxl, cnts, u_rand, b, Wrow, Wt, slow, fastp, ctrl, out);
}